// Round 1
// 488.071 us; speedup vs baseline: 1.0417x; 1.0417x over previous
//
#include <hip/hip_runtime.h>
#include <cstdint>
#include <cstddef>

typedef _Float16 f16;
typedef __attribute__((ext_vector_type(4))) _Float16 f16x4;
typedef __attribute__((ext_vector_type(8))) _Float16 f16x8;
typedef __attribute__((ext_vector_type(4))) float f32x4;

#define MFMA_F16(a, b, c) __builtin_amdgcn_mfma_f32_16x16x32_f16((a), (b), (c), 0, 0, 0)

static constexpr int BB   = 8;
static constexpr int SS   = 2048;
static constexpr int DD   = 1024;
static constexpr int HALF = 512;
static constexpr int TILE = 256 * 32;   // f16 elems per K-tile slot (16 KB)

// async global->LDS, 16 B per lane; LDS dest is wave-uniform base + lane*16.
__device__ __forceinline__ void gll16(const f16* g, f16* lds) {
  __builtin_amdgcn_global_load_lds(
      (__attribute__((address_space(1))) void*)(g),
      (__attribute__((address_space(3))) void*)(lds), 16, 0, 0);
}

// ---------------------------------------------------------------------------
// Fused prep: blocks [0,1024) convert W (fp32->fp16); blocks [1024,1024+16384)
// build Xh = concat(t_out,c_out) fp16 for ALL 8 batches.
// ---------------------------------------------------------------------------
__global__ __launch_bounds__(256) void fused_prep(
    const float* __restrict__ Wq, const float* __restrict__ Wk, const float* __restrict__ Wv,
    const float* __restrict__ t_out, const float* __restrict__ c_out,
    f16* __restrict__ Whq, f16* __restrict__ Whk, f16* __restrict__ Whv,
    f16* __restrict__ Xh)
{
  if (blockIdx.x < 1024) {
    const int i = (blockIdx.x * 256 + threadIdx.x) * 4;
    const float4 q = *(const float4*)(Wq + i);
    const float4 k = *(const float4*)(Wk + i);
    const float4 v = *(const float4*)(Wv + i);
    f16x4 a;
    a.x = (f16)q.x; a.y = (f16)q.y; a.z = (f16)q.z; a.w = (f16)q.w; *(f16x4*)(Whq + i) = a;
    a.x = (f16)k.x; a.y = (f16)k.y; a.z = (f16)k.z; a.w = (f16)k.w; *(f16x4*)(Whk + i) = a;
    a.x = (f16)v.x; a.y = (f16)v.y; a.z = (f16)v.z; a.w = (f16)v.w; *(f16x4*)(Whv + i) = a;
  } else {
    const size_t i = ((size_t)(blockIdx.x - 1024) * 256 + threadIdx.x) * 4;
    const int d = (int)(i & 1023);
    const size_t g = i >> 10;  // global token 0..16383
    const float* src = (d < HALF) ? (t_out + g * HALF + d)
                                  : (c_out + g * HALF + (d - HALF));
    const float4 x = *(const float4*)src;
    f16x4 h;
    h.x = (f16)x.x; h.y = (f16)x.y; h.z = (f16)x.z; h.w = (f16)x.w;
    *(f16x4*)(Xh + i) = h;
  }
}

// ---------------------------------------------------------------------------
// Deep-pipelined 256x256x32 GEMM template pieces (8 waves / 512 threads).
//
// LDS layout per operand: ring of 4 K-tile slots, each [256 rows][32 f16].
// Physical 16B-granule swizzle: data of logical granule g of row r lives at
// physical granule g ^ ((r>>1)&3).  global_load_lds writes LINEARLY, so the
// swizzle is applied by permuting the per-lane GLOBAL source column; the
// ds_read applies the same XOR on its address (both-sides rule).
// ---------------------------------------------------------------------------
__device__ __forceinline__ void stage256(
    f16* slot, const f16* g, size_t row0, int ld, int k0, int wave, int lane)
{
#pragma unroll
  for (int q = 0; q < 2; ++q) {
    const int chunk = wave * 128 + q * 64 + lane;   // 16B chunk id in tile
    const int row   = chunk >> 2;                   // 4 chunks per 64B row
    const int lg    = (chunk & 3) ^ ((row >> 1) & 3); // logical granule
    gll16(g + (row0 + (size_t)row) * ld + k0 + lg * 8,
          slot + (size_t)(wave * 128 + q * 64) * 8);  // wave-uniform dest
  }
}

__device__ __forceinline__ void mma_step(
    const f16* at, const f16* bt, f32x4 acc[8][4],
    int wm, int wn, int col16, int quad)
{
  f16x8 af[8], bf[4];
#pragma unroll
  for (int j = 0; j < 4; ++j) {
    const int r = wn * 64 + j * 16 + col16;
    bf[j] = *(const f16x8*)&bt[r * 32 + ((quad ^ ((r >> 1) & 3)) * 8)];
  }
#pragma unroll
  for (int i = 0; i < 8; ++i) {
    const int r = wm * 128 + i * 16 + col16;
    af[i] = *(const f16x8*)&at[r * 32 + ((quad ^ ((r >> 1) & 3)) * 8)];
  }
  __builtin_amdgcn_s_setprio(1);
#pragma unroll
  for (int i = 0; i < 8; ++i)
#pragma unroll
    for (int j = 0; j < 4; ++j)
      acc[i][j] = MFMA_F16(af[i], bf[j], acc[i][j]);
  __builtin_amdgcn_s_setprio(0);
}

// Counted-vmcnt pipeline: prefetch distance 3, ring of 4 slots, ONE barrier
// per K-tile, vmcnt never drained to 0 until the last two peeled tiles.
// Correctness: (RAW) each wave waits vmcnt on ITS OWN staging loads, then the
// barrier makes the guarantee global.  (WAR) the stage of tile t+3 targets
// slot (t-1)&3, whose last reads retired (compiler lgkmcnt before MFMA use)
// before the barrier that precedes this stage.
template <int K>
__device__ __forceinline__ void mma_pipeline(
    const f16* __restrict__ A, const f16* __restrict__ B,
    int lda, int ldb, size_t arow0, size_t brow0,
    f16* As, f16* Bs, f32x4 acc[8][4],
    int wave, int lane, int wm, int wn, int col16, int quad)
{
  constexpr int NT = K / 32;   // >= 4 required (we have 32 or 64)
#pragma unroll
  for (int p = 0; p < 3; ++p) {
    stage256(As + p * TILE, A, arow0, lda, p * 32, wave, lane);
    stage256(Bs + p * TILE, B, brow0, ldb, p * 32, wave, lane);
  }
  for (int t = 0; t < NT - 3; ++t) {
    // tile t landed (outstanding = tiles t+1,t+2 = 8 gll); then sync waves.
    asm volatile("s_waitcnt vmcnt(8)\n\ts_barrier" ::: "memory");
    const int ps = (t + 3) & 3;
    stage256(As + ps * TILE, A, arow0, lda, (t + 3) * 32, wave, lane);
    stage256(Bs + ps * TILE, B, brow0, ldb, (t + 3) * 32, wave, lane);
    const int s = t & 3;
    mma_step(As + s * TILE, Bs + s * TILE, acc, wm, wn, col16, quad);
  }
  asm volatile("s_waitcnt vmcnt(8)\n\ts_barrier" ::: "memory");
  mma_step(As + ((NT - 3) & 3) * TILE, Bs + ((NT - 3) & 3) * TILE, acc, wm, wn, col16, quad);
  asm volatile("s_waitcnt vmcnt(4)\n\ts_barrier" ::: "memory");
  mma_step(As + ((NT - 2) & 3) * TILE, Bs + ((NT - 2) & 3) * TILE, acc, wm, wn, col16, quad);
  asm volatile("s_waitcnt vmcnt(0)\n\ts_barrier" ::: "memory");
  mma_step(As + ((NT - 1) & 3) * TILE, Bs + ((NT - 1) & 3) * TILE, acc, wm, wn, col16, quad);
}

// ---------------------------------------------------------------------------
// QKV projection. grid (64, 4, 3): x = m-tile (16384/256), y = n-tile
// (1024/256), z selects Q/K/V.
// ---------------------------------------------------------------------------
__global__ __launch_bounds__(512, 2) void proj_gemm(
    const f16* __restrict__ Xh,
    const f16* __restrict__ Whq, const f16* __restrict__ Whk, const f16* __restrict__ Whv,
    const float* __restrict__ bq, const float* __restrict__ bk, const float* __restrict__ bv,
    f16* __restrict__ Q, f16* __restrict__ K, f16* __restrict__ Vv)
{
  __shared__ alignas(16) f16 As[4 * TILE];
  __shared__ alignas(16) f16 Bs[4 * TILE];

  const int z = blockIdx.z;
  const f16* Wh = (z == 0) ? Whq : (z == 1) ? Whk : Whv;
  const float* bias = (z == 0) ? bq : (z == 1) ? bk : bv;
  f16* dst = (z == 0) ? Q : (z == 1) ? K : Vv;

  const int t = threadIdx.x, lane = t & 63, wave = t >> 6;
  const int wm = wave >> 2, wn = wave & 3, col16 = lane & 15, quad = lane >> 4;
  const int m0 = blockIdx.x * 256, n0 = blockIdx.y * 256;

  f32x4 acc[8][4];
#pragma unroll
  for (int i = 0; i < 8; ++i)
#pragma unroll
    for (int j = 0; j < 4; ++j) acc[i][j] = f32x4{0.f, 0.f, 0.f, 0.f};

  mma_pipeline<DD>(Xh, Wh, DD, DD, (size_t)m0, (size_t)n0,
                   As, Bs, acc, wave, lane, wm, wn, col16, quad);

#pragma unroll
  for (int j = 0; j < 4; ++j) {
    const int gn = n0 + wn * 64 + j * 16 + col16;
    const float bb_ = bias[gn];
#pragma unroll
    for (int i = 0; i < 8; ++i) {
      const int gm = m0 + wm * 128 + i * 16 + quad * 4;
#pragma unroll
      for (int r = 0; r < 4; ++r)
        dst[(size_t)(gm + r) * DD + gn] = (f16)(acc[i][j][r] + bb_);
    }
  }
}

// ---------------------------------------------------------------------------
// Transpose V [b][s][e] -> Vt [b][e][s], full batch (grid 32,16,8)
// ---------------------------------------------------------------------------
__global__ __launch_bounds__(256) void transpose_v(
    const f16* __restrict__ Vv, f16* __restrict__ Vt)
{
  __shared__ alignas(16) f16 tile[64][72];
  const int b  = blockIdx.z;
  const int s0 = blockIdx.x * 64;
  const int e0 = blockIdx.y * 64;
  const int t  = threadIdx.x;
  const int r  = t >> 3;
  const int c8 = (t & 7) * 8;

  const f16* src0 = Vv + ((size_t)(b * SS + s0 + r)) * DD + e0 + c8;
  const f16* src1 = Vv + ((size_t)(b * SS + s0 + r + 32)) * DD + e0 + c8;
  *(int4*)&tile[r][c8]      = *(const int4*)src0;
  *(int4*)&tile[r + 32][c8] = *(const int4*)src1;
  __syncthreads();

  f16x8 v0, v1;
#pragma unroll
  for (int u = 0; u < 8; ++u) {
    v0[u] = tile[c8 + u][r];
    v1[u] = tile[c8 + u][r + 32];
  }
  f16* dst0 = Vt + ((size_t)b * DD + e0 + r) * SS + s0 + c8;
  f16* dst1 = Vt + ((size_t)b * DD + e0 + r + 32) * SS + s0 + c8;
  *(f16x8*)dst0 = v0;
  *(f16x8*)dst1 = v1;
}

// ---------------------------------------------------------------------------
// Scores for chunk [b0, b0+c): grid (8, 8, c), 256x256 tiles.
// ---------------------------------------------------------------------------
__global__ __launch_bounds__(512, 2) void qk_gemm(
    const f16* __restrict__ Q, const f16* __restrict__ K, f16* __restrict__ Sc,
    int b0)
{
  __shared__ alignas(16) f16 As[4 * TILE];
  __shared__ alignas(16) f16 Bs[4 * TILE];

  const int bb = blockIdx.z;
  const int t = threadIdx.x, lane = t & 63, wave = t >> 6;
  const int wm = wave >> 2, wn = wave & 3, col16 = lane & 15, quad = lane >> 4;
  const int m0 = blockIdx.y * 256, n0 = blockIdx.x * 256;

  const size_t arow0 = (size_t)(b0 + bb) * SS + m0;
  const size_t brow0 = (size_t)(b0 + bb) * SS + n0;

  f32x4 acc[8][4];
#pragma unroll
  for (int i = 0; i < 8; ++i)
#pragma unroll
    for (int j = 0; j < 4; ++j) acc[i][j] = f32x4{0.f, 0.f, 0.f, 0.f};

  mma_pipeline<DD>(Q, K, DD, DD, arow0, brow0,
                   As, Bs, acc, wave, lane, wm, wn, col16, quad);

#pragma unroll
  for (int i = 0; i < 8; ++i)
#pragma unroll
    for (int j = 0; j < 4; ++j)
#pragma unroll
      for (int r = 0; r < 4; ++r) {
        const int gm = m0 + wm * 128 + i * 16 + quad * 4 + r;
        const int gn = n0 + wn * 64 + j * 16 + col16;
        Sc[((size_t)bb * SS + gm) * SS + gn] = (f16)acc[i][j][r];
      }
}

// ---------------------------------------------------------------------------
// Row softmax fp16 -> fp16, in place (row = 2048 f16; 256 thr x f16x8).
// ---------------------------------------------------------------------------
__global__ __launch_bounds__(256) void softmax_rows(f16* __restrict__ Sc)
{
  const size_t row = blockIdx.x;
  f16* p = Sc + row * SS;
  const int t = threadIdx.x;

  const f16x8 v = *(const f16x8*)(p + t * 8);
  float xs[8];
#pragma unroll
  for (int u = 0; u < 8; ++u) xs[u] = (float)v[u];

  float m = xs[0];
#pragma unroll
  for (int u = 1; u < 8; ++u) m = fmaxf(m, xs[u]);
#pragma unroll
  for (int off = 32; off > 0; off >>= 1) m = fmaxf(m, __shfl_xor(m, off));
  __shared__ float redm[4];
  __shared__ float reds[4];
  if ((t & 63) == 0) redm[t >> 6] = m;
  __syncthreads();
  m = fmaxf(fmaxf(redm[0], redm[1]), fmaxf(redm[2], redm[3]));

  float e[8];
  float s = 0.f;
#pragma unroll
  for (int u = 0; u < 8; ++u) {
    e[u] = expf(xs[u] - m);
    s += e[u];
  }
#pragma unroll
  for (int off = 32; off > 0; off >>= 1) s += __shfl_xor(s, off);
  if ((t & 63) == 0) reds[t >> 6] = s;
  __syncthreads();
  s = reds[0] + reds[1] + reds[2] + reds[3];
  const float inv = 1.0f / s;

  f16x8 o;
#pragma unroll
  for (int u = 0; u < 8; ++u) o[u] = (f16)(e[u] * inv);
  *(f16x8*)(p + t * 8) = o;
}

// ---------------------------------------------------------------------------
// Output: out[(b0+bb)][s][e] = sum_j P[bb][s][j] * Vt[b0+bb][e][j]
// grid (4, 8, c), 256x256 tiles, K = SS = 2048.
// ---------------------------------------------------------------------------
__global__ __launch_bounds__(512, 2) void pv_gemm(
    const f16* __restrict__ P, const f16* __restrict__ Vt, float* __restrict__ out,
    int b0)
{
  __shared__ alignas(16) f16 As[4 * TILE];
  __shared__ alignas(16) f16 Bs[4 * TILE];

  const int bb = blockIdx.z;
  const int t = threadIdx.x, lane = t & 63, wave = t >> 6;
  const int wm = wave >> 2, wn = wave & 3, col16 = lane & 15, quad = lane >> 4;
  const int m0 = blockIdx.y * 256;  // s
  const int n0 = blockIdx.x * 256;  // e

  const size_t arow0 = (size_t)bb * SS + m0;         // P rows (pitch SS)
  const size_t brow0 = (size_t)(b0 + bb) * DD + n0;  // Vt rows (pitch SS)

  f32x4 acc[8][4];
#pragma unroll
  for (int i = 0; i < 8; ++i)
#pragma unroll
    for (int j = 0; j < 4; ++j) acc[i][j] = f32x4{0.f, 0.f, 0.f, 0.f};

  mma_pipeline<SS>(P, Vt, SS, SS, arow0, brow0,
                   As, Bs, acc, wave, lane, wm, wn, col16, quad);

#pragma unroll
  for (int i = 0; i < 8; ++i)
#pragma unroll
    for (int j = 0; j < 4; ++j)
#pragma unroll
      for (int r = 0; r < 4; ++r) {
        const int gm = m0 + wm * 128 + i * 16 + quad * 4 + r;
        const int gn = n0 + wn * 64 + j * 16 + col16;
        out[((size_t)(b0 + bb) * SS + gm) * DD + gn] = acc[i][j][r];
      }
}

// ---------------------------------------------------------------------------
extern "C" void kernel_launch(void* const* d_in, const int* in_sizes, int n_in,
                              void* d_out, int out_size, void* d_ws, size_t ws_size,
                              hipStream_t stream)
{
  const float* t_out = (const float*)d_in[0];
  const float* c_out = (const float*)d_in[1];
  const float* Wq    = (const float*)d_in[2];
  const float* bq    = (const float*)d_in[3];
  const float* Wk    = (const float*)d_in[4];
  const float* bk    = (const float*)d_in[5];
  const float* Wv    = (const float*)d_in[6];
  const float* bv    = (const float*)d_in[7];
  float* out = (float*)d_out;

  // ---- sizes ----
  const size_t WELT  = (size_t)DD * DD;
  const size_t TD8   = (size_t)BB * SS * DD;             // 16.7M elems
  const size_t XH_B  = TD8 * sizeof(f16);                // 33.55 MB
  const size_t SC1_B = (size_t)SS * SS * sizeof(f16);    // 8.39 MB per batch

  // ---- pick Sc chunk c (pure function of ws_size -> graph-safe) ----
  const size_t FIXED = 3 * WELT * sizeof(f16) + 4 * XH_B;  // 140.5 MB
  int c = 2;
  for (int cand : {8, 4}) {
    size_t xsc = (size_t)cand * SC1_B;
    if (xsc < XH_B) xsc = XH_B;
    if (FIXED + xsc <= ws_size) { c = cand; break; }
  }
  size_t xsc_bytes = (size_t)c * SC1_B;
  if (xsc_bytes < XH_B) xsc_bytes = XH_B;

  // ---- layout: [W][Xh|Sc(alias)][Q][K][Vv][Vt] ----
  char* ws = (char*)d_ws;
  f16* Whq = (f16*)ws;
  f16* Whk = Whq + WELT;
  f16* Whv = Whk + WELT;
  char* XSc = (char*)(Whv + WELT);
  f16* Xh = (f16*)XSc;     // live during prep/proj
  f16* Sc = (f16*)XSc;     // live during attention chunks (aliases Xh)
  f16* Q  = (f16*)(XSc + xsc_bytes);
  f16* K  = Q  + TD8;
  f16* Vv = K  + TD8;
  f16* Vt = Vv + TD8;

  fused_prep<<<dim3(1024 + 16384), dim3(256), 0, stream>>>(
      Wq, Wk, Wv, t_out, c_out, Whq, Whk, Whv, Xh);
  proj_gemm<<<dim3(64, 4, 3), dim3(512), 0, stream>>>(
      Xh, Whq, Whk, Whv, bq, bk, bv, Q, K, Vv);
  transpose_v<<<dim3(32, 16, 8), dim3(256), 0, stream>>>(Vv, Vt);

  for (int b0 = 0; b0 < BB; b0 += c) {
    qk_gemm<<<dim3(8, 8, c), dim3(512), 0, stream>>>(Q, K, Sc, b0);
    softmax_rows<<<dim3(c * SS), dim3(256), 0, stream>>>(Sc);
    pv_gemm<<<dim3(4, 8, c), dim3(512), 0, stream>>>(Sc, Vt, out, b0);
  }
}

// Round 2
// 437.254 us; speedup vs baseline: 1.1628x; 1.1162x over previous
//
#include <hip/hip_runtime.h>
#include <cstdint>
#include <cstddef>

typedef _Float16 f16;
typedef __attribute__((ext_vector_type(4))) _Float16 f16x4;
typedef __attribute__((ext_vector_type(8))) _Float16 f16x8;
typedef __attribute__((ext_vector_type(4))) float f32x4;

#define MFMA_F16(a, b, c) __builtin_amdgcn_mfma_f32_16x16x32_f16((a), (b), (c), 0, 0, 0)

static constexpr int BB   = 8;
static constexpr int SS   = 2048;
static constexpr int DD   = 1024;
static constexpr int HALF = 512;
static constexpr int T32  = 256 * 32;   // f16 elems per K-tile slot (16 KB)

// async global->LDS, 16 B per lane; LDS dest is wave-uniform base + lane*16.
__device__ __forceinline__ void gll16(const f16* g, f16* lds) {
  __builtin_amdgcn_global_load_lds(
      (__attribute__((address_space(1))) void*)(g),
      (__attribute__((address_space(3))) void*)(lds), 16, 0, 0);
}

// ---------------------------------------------------------------------------
// Fused prep: blocks [0,1024) convert W (fp32->fp16); blocks [1024,1024+16384)
// build Xh = concat(t_out,c_out) fp16 for ALL 8 batches.
// ---------------------------------------------------------------------------
__global__ __launch_bounds__(256) void fused_prep(
    const float* __restrict__ Wq, const float* __restrict__ Wk, const float* __restrict__ Wv,
    const float* __restrict__ t_out, const float* __restrict__ c_out,
    f16* __restrict__ Whq, f16* __restrict__ Whk, f16* __restrict__ Whv,
    f16* __restrict__ Xh)
{
  if (blockIdx.x < 1024) {
    const int i = (blockIdx.x * 256 + threadIdx.x) * 4;
    const float4 q = *(const float4*)(Wq + i);
    const float4 k = *(const float4*)(Wk + i);
    const float4 v = *(const float4*)(Wv + i);
    f16x4 a;
    a.x = (f16)q.x; a.y = (f16)q.y; a.z = (f16)q.z; a.w = (f16)q.w; *(f16x4*)(Whq + i) = a;
    a.x = (f16)k.x; a.y = (f16)k.y; a.z = (f16)k.z; a.w = (f16)k.w; *(f16x4*)(Whk + i) = a;
    a.x = (f16)v.x; a.y = (f16)v.y; a.z = (f16)v.z; a.w = (f16)v.w; *(f16x4*)(Whv + i) = a;
  } else {
    const size_t i = ((size_t)(blockIdx.x - 1024) * 256 + threadIdx.x) * 4;
    const int d = (int)(i & 1023);
    const size_t g = i >> 10;  // global token 0..16383
    const float* src = (d < HALF) ? (t_out + g * HALF + d)
                                  : (c_out + g * HALF + (d - HALF));
    const float4 x = *(const float4*)src;
    f16x4 h;
    h.x = (f16)x.x; h.y = (f16)x.y; h.z = (f16)x.z; h.w = (f16)x.w;
    *(f16x4*)(Xh + i) = h;
  }
}

// ---------------------------------------------------------------------------
// Fine-phased 256x256 GEMM, BK=32, 8 waves (512 thr), wave C = 128x64.
// LDS: ring of 4 K-tile slots per operand ([256][32] f16, 16 KB) = 128 KiB.
// Swizzle: 16B granule g of row r lives at physical granule g ^ ((r>>1)&3);
// applied on the global SOURCE column (LDS dest linear, required by
// global_load_lds) and on the ds_read address (both-sides rule).
// Per K-tile: 2 phases; each = {vmcnt+barrier, stage half-tile, ds_read
// subtile, setprio(1), 16 MFMA, setprio(0)}.  vmcnt(8) = last 4 phases
// (tiles t+1,t+2) in flight; tile t proven landed at its entry barrier.
// ---------------------------------------------------------------------------
__device__ __forceinline__ void stage_half(
    f16* s, const f16* g, size_t r0, int ld, int k0, int u, int w4, int rr, int gg)
{
#pragma unroll
  for (int q = 0; q < 2; ++q) {
    const int rb  = u * 128 + w4 * 32 + q * 16;   // wave-uniform row block
    const int row = rb + rr;
    const int lg  = gg ^ ((row >> 1) & 3);        // pre-swizzled source granule
    gll16(g + (r0 + (size_t)row) * ld + k0 + lg * 8, s + (size_t)rb * 32);
  }
}

template <int K>
__device__ __forceinline__ void mma_pipeline(
    const f16* __restrict__ A, const f16* __restrict__ B,
    int lda, int ldb, size_t arow0, size_t brow0,
    f16* As, f16* Bs, f32x4 acc[8][4],
    int wave, int lane, int wm, int wn, int col16, int quad)
{
  constexpr int NT = K / 32;            // 32 or 64 here (>= 4 required)
  const int w4 = wave & 3, rr = lane >> 2, gg = lane & 3;
  // this wave stages either A (waves 0-3) or B (waves 4-7)
  const f16*  g_st  = (wave < 4) ? A : B;
  const size_t r0_st = (wave < 4) ? arow0 : brow0;
  const int    ld_st = (wave < 4) ? lda : ldb;
  f16*         ring  = (wave < 4) ? As : Bs;

  // prologue: tiles 0,1,2 fully staged (12 gll / wave)
#pragma unroll
  for (int pt = 0; pt < 3; ++pt)
#pragma unroll
    for (int u = 0; u < 2; ++u)
      stage_half(ring + pt * T32, g_st, r0_st, ld_st, pt * 32, u, w4, rr, gg);

  for (int t = 0; t < NT; ++t) {
    const f16* At = As + (t & 3) * T32;
    const f16* Bt = Bs + (t & 3) * T32;
    f16* Sn = ring + ((t + 3) & 3) * T32;
    const bool st = (t + 3 < NT);
    const int kn = (t + 3) * 32;

    f16x8 a[4], b[4];

    // ---------------- phase 0: rows wm*128 + [0,64), all 4 N-frags --------
    if (t < NT - 2)       asm volatile("s_waitcnt vmcnt(8)\n\ts_barrier" ::: "memory");
    else if (t == NT - 2) asm volatile("s_waitcnt vmcnt(4)\n\ts_barrier" ::: "memory");
    else                  asm volatile("s_waitcnt vmcnt(0)\n\ts_barrier" ::: "memory");
    if (st) stage_half(Sn, g_st, r0_st, ld_st, kn, 0, w4, rr, gg);
#pragma unroll
    for (int j = 0; j < 4; ++j) {
      const int r = wn * 64 + j * 16 + col16;
      b[j] = *(const f16x8*)&Bt[r * 32 + ((quad ^ ((r >> 1) & 3)) << 3)];
    }
#pragma unroll
    for (int i = 0; i < 4; ++i) {
      const int r = wm * 128 + i * 16 + col16;
      a[i] = *(const f16x8*)&At[r * 32 + ((quad ^ ((r >> 1) & 3)) << 3)];
    }
    __builtin_amdgcn_s_setprio(1);
#pragma unroll
    for (int i = 0; i < 4; ++i)
#pragma unroll
      for (int j = 0; j < 4; ++j)
        acc[i][j] = MFMA_F16(a[i], b[j], acc[i][j]);
    __builtin_amdgcn_s_setprio(0);

    // ---------------- phase 1: rows wm*128 + [64,128), reuse b[] ----------
    if (t < NT - 2)       asm volatile("s_waitcnt vmcnt(8)\n\ts_barrier" ::: "memory");
    else if (t == NT - 2) asm volatile("s_waitcnt vmcnt(4)\n\ts_barrier" ::: "memory");
    else                  asm volatile("s_waitcnt vmcnt(0)\n\ts_barrier" ::: "memory");
    if (st) stage_half(Sn, g_st, r0_st, ld_st, kn, 1, w4, rr, gg);
#pragma unroll
    for (int i = 0; i < 4; ++i) {
      const int r = wm * 128 + 64 + i * 16 + col16;
      a[i] = *(const f16x8*)&At[r * 32 + ((quad ^ ((r >> 1) & 3)) << 3)];
    }
    __builtin_amdgcn_s_setprio(1);
#pragma unroll
    for (int i = 0; i < 4; ++i)
#pragma unroll
      for (int j = 0; j < 4; ++j)
        acc[i + 4][j] = MFMA_F16(a[i], b[j], acc[i + 4][j]);
    __builtin_amdgcn_s_setprio(0);
  }
}

// ---------------------------------------------------------------------------
// QKV projection. grid (64, 4, 3): x = m-tile, y = n-tile, z = Q/K/V.
// ---------------------------------------------------------------------------
__global__ __launch_bounds__(512, 2) void proj_gemm(
    const f16* __restrict__ Xh,
    const f16* __restrict__ Whq, const f16* __restrict__ Whk, const f16* __restrict__ Whv,
    const float* __restrict__ bq, const float* __restrict__ bk, const float* __restrict__ bv,
    f16* __restrict__ Q, f16* __restrict__ K, f16* __restrict__ Vv)
{
  __shared__ alignas(16) f16 As[4 * T32];
  __shared__ alignas(16) f16 Bs[4 * T32];

  const int z = blockIdx.z;
  const f16* Wh = (z == 0) ? Whq : (z == 1) ? Whk : Whv;
  const float* bias = (z == 0) ? bq : (z == 1) ? bk : bv;
  f16* dst = (z == 0) ? Q : (z == 1) ? K : Vv;

  const int t = threadIdx.x, lane = t & 63, wave = t >> 6;
  const int wm = wave >> 2, wn = wave & 3, col16 = lane & 15, quad = lane >> 4;
  const int m0 = blockIdx.x * 256, n0 = blockIdx.y * 256;

  f32x4 acc[8][4];
#pragma unroll
  for (int i = 0; i < 8; ++i)
#pragma unroll
    for (int j = 0; j < 4; ++j) acc[i][j] = f32x4{0.f, 0.f, 0.f, 0.f};

  mma_pipeline<DD>(Xh, Wh, DD, DD, (size_t)m0, (size_t)n0,
                   As, Bs, acc, wave, lane, wm, wn, col16, quad);

#pragma unroll
  for (int j = 0; j < 4; ++j) {
    const int gn = n0 + wn * 64 + j * 16 + col16;
    const float bb_ = bias[gn];
#pragma unroll
    for (int i = 0; i < 8; ++i) {
      const int gm = m0 + wm * 128 + i * 16 + quad * 4;
#pragma unroll
      for (int r = 0; r < 4; ++r)
        dst[(size_t)(gm + r) * DD + gn] = (f16)(acc[i][j][r] + bb_);
    }
  }
}

// ---------------------------------------------------------------------------
// Transpose V [b][s][e] -> Vt [b][e][s], full batch (grid 32,16,8)
// ---------------------------------------------------------------------------
__global__ __launch_bounds__(256) void transpose_v(
    const f16* __restrict__ Vv, f16* __restrict__ Vt)
{
  __shared__ alignas(16) f16 tile[64][72];
  const int b  = blockIdx.z;
  const int s0 = blockIdx.x * 64;
  const int e0 = blockIdx.y * 64;
  const int t  = threadIdx.x;
  const int r  = t >> 3;
  const int c8 = (t & 7) * 8;

  const f16* src0 = Vv + ((size_t)(b * SS + s0 + r)) * DD + e0 + c8;
  const f16* src1 = Vv + ((size_t)(b * SS + s0 + r + 32)) * DD + e0 + c8;
  *(int4*)&tile[r][c8]      = *(const int4*)src0;
  *(int4*)&tile[r + 32][c8] = *(const int4*)src1;
  __syncthreads();

  f16x8 v0, v1;
#pragma unroll
  for (int u = 0; u < 8; ++u) {
    v0[u] = tile[c8 + u][r];
    v1[u] = tile[c8 + u][r + 32];
  }
  f16* dst0 = Vt + ((size_t)b * DD + e0 + r) * SS + s0 + c8;
  f16* dst1 = Vt + ((size_t)b * DD + e0 + r + 32) * SS + s0 + c8;
  *(f16x8*)dst0 = v0;
  *(f16x8*)dst1 = v1;
}

// ---------------------------------------------------------------------------
// Scores for chunk [b0, b0+c): grid (8, 8, c), 256x256 tiles.
// ---------------------------------------------------------------------------
__global__ __launch_bounds__(512, 2) void qk_gemm(
    const f16* __restrict__ Q, const f16* __restrict__ K, f16* __restrict__ Sc,
    int b0)
{
  __shared__ alignas(16) f16 As[4 * T32];
  __shared__ alignas(16) f16 Bs[4 * T32];

  const int bb = blockIdx.z;
  const int t = threadIdx.x, lane = t & 63, wave = t >> 6;
  const int wm = wave >> 2, wn = wave & 3, col16 = lane & 15, quad = lane >> 4;
  const int m0 = blockIdx.y * 256, n0 = blockIdx.x * 256;

  const size_t arow0 = (size_t)(b0 + bb) * SS + m0;
  const size_t brow0 = (size_t)(b0 + bb) * SS + n0;

  f32x4 acc[8][4];
#pragma unroll
  for (int i = 0; i < 8; ++i)
#pragma unroll
    for (int j = 0; j < 4; ++j) acc[i][j] = f32x4{0.f, 0.f, 0.f, 0.f};

  mma_pipeline<DD>(Q, K, DD, DD, arow0, brow0,
                   As, Bs, acc, wave, lane, wm, wn, col16, quad);

#pragma unroll
  for (int i = 0; i < 8; ++i)
#pragma unroll
    for (int j = 0; j < 4; ++j)
#pragma unroll
      for (int r = 0; r < 4; ++r) {
        const int gm = m0 + wm * 128 + i * 16 + quad * 4 + r;
        const int gn = n0 + wn * 64 + j * 16 + col16;
        Sc[((size_t)bb * SS + gm) * SS + gn] = (f16)acc[i][j][r];
      }
}

// ---------------------------------------------------------------------------
// Row softmax fp16 -> fp16, in place (row = 2048 f16; 256 thr x f16x8).
// ---------------------------------------------------------------------------
__global__ __launch_bounds__(256) void softmax_rows(f16* __restrict__ Sc)
{
  const size_t row = blockIdx.x;
  f16* p = Sc + row * SS;
  const int t = threadIdx.x;

  const f16x8 v = *(const f16x8*)(p + t * 8);
  float xs[8];
#pragma unroll
  for (int u = 0; u < 8; ++u) xs[u] = (float)v[u];

  float m = xs[0];
#pragma unroll
  for (int u = 1; u < 8; ++u) m = fmaxf(m, xs[u]);
#pragma unroll
  for (int off = 32; off > 0; off >>= 1) m = fmaxf(m, __shfl_xor(m, off));
  __shared__ float redm[4];
  __shared__ float reds[4];
  if ((t & 63) == 0) redm[t >> 6] = m;
  __syncthreads();
  m = fmaxf(fmaxf(redm[0], redm[1]), fmaxf(redm[2], redm[3]));

  float e[8];
  float s = 0.f;
#pragma unroll
  for (int u = 0; u < 8; ++u) {
    e[u] = expf(xs[u] - m);
    s += e[u];
  }
#pragma unroll
  for (int off = 32; off > 0; off >>= 1) s += __shfl_xor(s, off);
  if ((t & 63) == 0) reds[t >> 6] = s;
  __syncthreads();
  s = reds[0] + reds[1] + reds[2] + reds[3];
  const float inv = 1.0f / s;

  f16x8 o;
#pragma unroll
  for (int u = 0; u < 8; ++u) o[u] = (f16)(e[u] * inv);
  *(f16x8*)(p + t * 8) = o;
}

// ---------------------------------------------------------------------------
// Output: out[(b0+bb)][s][e] = sum_j P[bb][s][j] * Vt[b0+bb][e][j]
// grid (4, 8, c), 256x256 tiles, K = SS = 2048.
// ---------------------------------------------------------------------------
__global__ __launch_bounds__(512, 2) void pv_gemm(
    const f16* __restrict__ P, const f16* __restrict__ Vt, float* __restrict__ out,
    int b0)
{
  __shared__ alignas(16) f16 As[4 * T32];
  __shared__ alignas(16) f16 Bs[4 * T32];

  const int bb = blockIdx.z;
  const int t = threadIdx.x, lane = t & 63, wave = t >> 6;
  const int wm = wave >> 2, wn = wave & 3, col16 = lane & 15, quad = lane >> 4;
  const int m0 = blockIdx.y * 256;  // s
  const int n0 = blockIdx.x * 256;  // e

  const size_t arow0 = (size_t)bb * SS + m0;         // P rows (pitch SS)
  const size_t brow0 = (size_t)(b0 + bb) * DD + n0;  // Vt rows (pitch SS)

  f32x4 acc[8][4];
#pragma unroll
  for (int i = 0; i < 8; ++i)
#pragma unroll
    for (int j = 0; j < 4; ++j) acc[i][j] = f32x4{0.f, 0.f, 0.f, 0.f};

  mma_pipeline<SS>(P, Vt, SS, SS, arow0, brow0,
                   As, Bs, acc, wave, lane, wm, wn, col16, quad);

#pragma unroll
  for (int i = 0; i < 8; ++i)
#pragma unroll
    for (int j = 0; j < 4; ++j)
#pragma unroll
      for (int r = 0; r < 4; ++r) {
        const int gm = m0 + wm * 128 + i * 16 + quad * 4 + r;
        const int gn = n0 + wn * 64 + j * 16 + col16;
        out[((size_t)(b0 + bb) * SS + gm) * DD + gn] = acc[i][j][r];
      }
}

// ---------------------------------------------------------------------------
extern "C" void kernel_launch(void* const* d_in, const int* in_sizes, int n_in,
                              void* d_out, int out_size, void* d_ws, size_t ws_size,
                              hipStream_t stream)
{
  const float* t_out = (const float*)d_in[0];
  const float* c_out = (const float*)d_in[1];
  const float* Wq    = (const float*)d_in[2];
  const float* bq    = (const float*)d_in[3];
  const float* Wk    = (const float*)d_in[4];
  const float* bk    = (const float*)d_in[5];
  const float* Wv    = (const float*)d_in[6];
  const float* bv    = (const float*)d_in[7];
  float* out = (float*)d_out;

  // ---- sizes ----
  const size_t WELT  = (size_t)DD * DD;
  const size_t TD8   = (size_t)BB * SS * DD;             // 16.7M elems
  const size_t XH_B  = TD8 * sizeof(f16);                // 33.55 MB
  const size_t SC1_B = (size_t)SS * SS * sizeof(f16);    // 8.39 MB per batch

  // ---- pick Sc chunk c (pure function of ws_size -> graph-safe) ----
  const size_t FIXED = 3 * WELT * sizeof(f16) + 4 * XH_B;  // 140.5 MB
  int c = 2;
  for (int cand : {8, 4}) {
    size_t xsc = (size_t)cand * SC1_B;
    if (xsc < XH_B) xsc = XH_B;
    if (FIXED + xsc <= ws_size) { c = cand; break; }
  }
  size_t xsc_bytes = (size_t)c * SC1_B;
  if (xsc_bytes < XH_B) xsc_bytes = XH_B;

  // ---- layout: [W][Xh|Sc(alias)][Q][K][Vv][Vt] ----
  char* ws = (char*)d_ws;
  f16* Whq = (f16*)ws;
  f16* Whk = Whq + WELT;
  f16* Whv = Whk + WELT;
  char* XSc = (char*)(Whv + WELT);
  f16* Xh = (f16*)XSc;     // live during prep/proj
  f16* Sc = (f16*)XSc;     // live during attention chunks (aliases Xh)
  f16* Q  = (f16*)(XSc + xsc_bytes);
  f16* K  = Q  + TD8;
  f16* Vv = K  + TD8;
  f16* Vt = Vv + TD8;

  fused_prep<<<dim3(1024 + 16384), dim3(256), 0, stream>>>(
      Wq, Wk, Wv, t_out, c_out, Whq, Whk, Whv, Xh);
  proj_gemm<<<dim3(64, 4, 3), dim3(512), 0, stream>>>(
      Xh, Whq, Whk, Whv, bq, bk, bv, Q, K, Vv);
  transpose_v<<<dim3(32, 16, 8), dim3(256), 0, stream>>>(Vv, Vt);

  for (int b0 = 0; b0 < BB; b0 += c) {
    qk_gemm<<<dim3(8, 8, c), dim3(512), 0, stream>>>(Q, K, Sc, b0);
    softmax_rows<<<dim3(c * SS), dim3(256), 0, stream>>>(Sc);
    pv_gemm<<<dim3(4, 8, c), dim3(512), 0, stream>>>(Sc, Vt, out, b0);
  }
}

// Round 3
// 430.367 us; speedup vs baseline: 1.1814x; 1.0160x over previous
//
#include <hip/hip_runtime.h>
#include <cstdint>
#include <cstddef>

typedef _Float16 f16;
typedef __attribute__((ext_vector_type(4))) _Float16 f16x4;
typedef __attribute__((ext_vector_type(8))) _Float16 f16x8;
typedef __attribute__((ext_vector_type(4))) float f32x4;

#define MFMA_F16(a, b, c) __builtin_amdgcn_mfma_f32_16x16x32_f16((a), (b), (c), 0, 0, 0)

static constexpr int BB   = 8;
static constexpr int SS   = 2048;
static constexpr int DD   = 1024;
static constexpr int HALF = 512;
static constexpr int T32  = 256 * 32;   // f16 elems per K-tile slot (16 KB)

// async global->LDS, 16 B per lane; LDS dest is wave-uniform base + lane*16.
__device__ __forceinline__ void gll16(const f16* g, f16* lds) {
  __builtin_amdgcn_global_load_lds(
      (__attribute__((address_space(1))) void*)(g),
      (__attribute__((address_space(3))) void*)(lds), 16, 0, 0);
}

// Bijective XCD-aware block remap (valid when nwg % 8 == 0; all GEMM grids
// here qualify).  Blocks with lin%8==x land on XCD x; give each XCD a
// contiguous chunk so same-XCD blocks share operand panels in its L2.
__device__ __forceinline__ dim3 xcd_swz() {
  const int gx = gridDim.x, gy = gridDim.y;
  const int lin = blockIdx.x + gx * (blockIdx.y + gy * blockIdx.z);
  const int nwg = gx * gy * (int)gridDim.z;
  const int q = nwg >> 3;
  const int nlin = (lin & 7) * q + (lin >> 3);
  dim3 r;
  r.x = nlin % gx;
  const int rest = nlin / gx;
  r.y = rest % gy;
  r.z = rest / gy;
  return r;
}

// ---------------------------------------------------------------------------
// Fused prep: blocks [0,1024) convert W (fp32->fp16); blocks [1024,1024+16384)
// build Xh = concat(t_out,c_out) fp16 for ALL 8 batches.
// ---------------------------------------------------------------------------
__global__ __launch_bounds__(256) void fused_prep(
    const float* __restrict__ Wq, const float* __restrict__ Wk, const float* __restrict__ Wv,
    const float* __restrict__ t_out, const float* __restrict__ c_out,
    f16* __restrict__ Whq, f16* __restrict__ Whk, f16* __restrict__ Whv,
    f16* __restrict__ Xh)
{
  if (blockIdx.x < 1024) {
    const int i = (blockIdx.x * 256 + threadIdx.x) * 4;
    const float4 q = *(const float4*)(Wq + i);
    const float4 k = *(const float4*)(Wk + i);
    const float4 v = *(const float4*)(Wv + i);
    f16x4 a;
    a.x = (f16)q.x; a.y = (f16)q.y; a.z = (f16)q.z; a.w = (f16)q.w; *(f16x4*)(Whq + i) = a;
    a.x = (f16)k.x; a.y = (f16)k.y; a.z = (f16)k.z; a.w = (f16)k.w; *(f16x4*)(Whk + i) = a;
    a.x = (f16)v.x; a.y = (f16)v.y; a.z = (f16)v.z; a.w = (f16)v.w; *(f16x4*)(Whv + i) = a;
  } else {
    const size_t i = ((size_t)(blockIdx.x - 1024) * 256 + threadIdx.x) * 4;
    const int d = (int)(i & 1023);
    const size_t g = i >> 10;  // global token 0..16383
    const float* src = (d < HALF) ? (t_out + g * HALF + d)
                                  : (c_out + g * HALF + (d - HALF));
    const float4 x = *(const float4*)src;
    f16x4 h;
    h.x = (f16)x.x; h.y = (f16)x.y; h.z = (f16)x.z; h.w = (f16)x.w;
    *(f16x4*)(Xh + i) = h;
  }
}

// ---------------------------------------------------------------------------
// 256x256 GEMM, BK=32, 8 waves (512 thr), wave C = 128x64, m201-style phases.
// LDS: ring of 4 K-tile slots per operand ([256][32] f16, 16 KB) = 128 KiB.
// Swizzle: 16B granule g of row r lives at physical granule g ^ ((r>>1)&3);
// applied on the global SOURCE column (LDS dest linear, required by
// global_load_lds) and on the ds_read address (both-sides rule).
//
// Phase = { ds_read subtile; stage 2 gll; [vmcnt at p0]; s_barrier;
//           lgkmcnt(0); sched_barrier; setprio(1); 16 MFMA; setprio(0);
//           s_barrier }.
// vmcnt ledger (4 gll per wave per tile, stage lead = 3 tiles):
//   at tile t phase 0 after staging: outstanding = t+1(4)+t+2(4)+t+3h0(2)=10;
//   vmcnt(6) retires exactly tile t+1 -> tile t+1 certified one tile EARLY,
//   so the pre-barrier ds_reads of tile t+1 at its phase 0 are race-free.
//   Tail: t==NT-3 -> vmcnt(4); t>=NT-2 -> vmcnt(0).
// WAR: stage at tile t targets slot (t+3)&3 == (t-1)&3 whose readers all
// passed tile t-1 phase-1's closing barrier.
// ---------------------------------------------------------------------------
__device__ __forceinline__ void stage_half(
    f16* s, const f16* g, size_t r0, int ld, int k0, int u, int w4, int rr, int gg)
{
#pragma unroll
  for (int q = 0; q < 2; ++q) {
    const int rb  = u * 128 + w4 * 32 + q * 16;   // wave-uniform row block
    const int row = rb + rr;
    const int lg  = gg ^ ((row >> 1) & 3);        // pre-swizzled source granule
    gll16(g + (r0 + (size_t)row) * ld + k0 + lg * 8, s + (size_t)rb * 32);
  }
}

template <int K>
__device__ __forceinline__ void mma_pipeline(
    const f16* __restrict__ A, const f16* __restrict__ B,
    int lda, int ldb, size_t arow0, size_t brow0,
    f16* As, f16* Bs, f32x4 acc[8][4],
    int wave, int lane, int wm, int wn, int col16, int quad)
{
  constexpr int NT = K / 32;            // 32 or 64 here (>= 4 required)
  const int w4 = wave & 3, rr = lane >> 2, gg = lane & 3;
  // this wave stages either A (waves 0-3) or B (waves 4-7)
  const f16*  g_st  = (wave < 4) ? A : B;
  const size_t r0_st = (wave < 4) ? arow0 : brow0;
  const int    ld_st = (wave < 4) ? lda : ldb;
  f16*         ring  = (wave < 4) ? As : Bs;

  // prologue: tiles 0,1,2 fully staged (12 gll / wave); certify tile 0.
#pragma unroll
  for (int pt = 0; pt < 3; ++pt)
#pragma unroll
    for (int u = 0; u < 2; ++u)
      stage_half(ring + pt * T32, g_st, r0_st, ld_st, pt * 32, u, w4, rr, gg);
  asm volatile("s_waitcnt vmcnt(8)" ::: "memory");
  __builtin_amdgcn_s_barrier();

  for (int t = 0; t < NT; ++t) {
    const f16* At = As + (t & 3) * T32;
    const f16* Bt = Bs + (t & 3) * T32;
    f16* Sn = ring + ((t + 3) & 3) * T32;
    const bool st = (t + 3 < NT);
    const int kn = (t + 3) * 32;

    f16x8 a[4], b[4];

    // ---------------- phase 0: rows wm*128 + [0,64), all 4 N-frags --------
#pragma unroll
    for (int j = 0; j < 4; ++j) {
      const int r = wn * 64 + j * 16 + col16;
      b[j] = *(const f16x8*)&Bt[r * 32 + ((quad ^ ((r >> 1) & 3)) << 3)];
    }
#pragma unroll
    for (int i = 0; i < 4; ++i) {
      const int r = wm * 128 + i * 16 + col16;
      a[i] = *(const f16x8*)&At[r * 32 + ((quad ^ ((r >> 1) & 3)) << 3)];
    }
    if (st) stage_half(Sn, g_st, r0_st, ld_st, kn, 0, w4, rr, gg);
    if (t < NT - 3)       asm volatile("s_waitcnt vmcnt(6)" ::: "memory");
    else if (t == NT - 3) asm volatile("s_waitcnt vmcnt(4)" ::: "memory");
    else                  asm volatile("s_waitcnt vmcnt(0)" ::: "memory");
    __builtin_amdgcn_s_barrier();
    asm volatile("s_waitcnt lgkmcnt(0)" ::: "memory");
    __builtin_amdgcn_sched_barrier(0);
    __builtin_amdgcn_s_setprio(1);
#pragma unroll
    for (int i = 0; i < 4; ++i)
#pragma unroll
      for (int j = 0; j < 4; ++j)
        acc[i][j] = MFMA_F16(a[i], b[j], acc[i][j]);
    __builtin_amdgcn_s_setprio(0);
    __builtin_amdgcn_s_barrier();

    // ---------------- phase 1: rows wm*128 + [64,128), reuse b[] ----------
#pragma unroll
    for (int i = 0; i < 4; ++i) {
      const int r = wm * 128 + 64 + i * 16 + col16;
      a[i] = *(const f16x8*)&At[r * 32 + ((quad ^ ((r >> 1) & 3)) << 3)];
    }
    if (st) stage_half(Sn, g_st, r0_st, ld_st, kn, 1, w4, rr, gg);
    __builtin_amdgcn_s_barrier();
    asm volatile("s_waitcnt lgkmcnt(0)" ::: "memory");
    __builtin_amdgcn_sched_barrier(0);
    __builtin_amdgcn_s_setprio(1);
#pragma unroll
    for (int i = 0; i < 4; ++i)
#pragma unroll
      for (int j = 0; j < 4; ++j)
        acc[i + 4][j] = MFMA_F16(a[i], b[j], acc[i + 4][j]);
    __builtin_amdgcn_s_setprio(0);
    __builtin_amdgcn_s_barrier();
  }
}

// ---------------------------------------------------------------------------
// QKV projection. grid (64, 4, 3): x = m-tile, y = n-tile, z = Q/K/V.
// ---------------------------------------------------------------------------
__global__ __launch_bounds__(512, 2) void proj_gemm(
    const f16* __restrict__ Xh,
    const f16* __restrict__ Whq, const f16* __restrict__ Whk, const f16* __restrict__ Whv,
    const float* __restrict__ bq, const float* __restrict__ bk, const float* __restrict__ bv,
    f16* __restrict__ Q, f16* __restrict__ K, f16* __restrict__ Vv)
{
  __shared__ alignas(16) f16 As[4 * T32];
  __shared__ alignas(16) f16 Bs[4 * T32];

  const dim3 bid = xcd_swz();
  const int z = bid.z;
  const f16* Wh = (z == 0) ? Whq : (z == 1) ? Whk : Whv;
  const float* bias = (z == 0) ? bq : (z == 1) ? bk : bv;
  f16* dst = (z == 0) ? Q : (z == 1) ? K : Vv;

  const int t = threadIdx.x, lane = t & 63, wave = t >> 6;
  const int wm = wave >> 2, wn = wave & 3, col16 = lane & 15, quad = lane >> 4;
  const int m0 = bid.x * 256, n0 = bid.y * 256;

  f32x4 acc[8][4];
#pragma unroll
  for (int i = 0; i < 8; ++i)
#pragma unroll
    for (int j = 0; j < 4; ++j) acc[i][j] = f32x4{0.f, 0.f, 0.f, 0.f};

  mma_pipeline<DD>(Xh, Wh, DD, DD, (size_t)m0, (size_t)n0,
                   As, Bs, acc, wave, lane, wm, wn, col16, quad);

#pragma unroll
  for (int j = 0; j < 4; ++j) {
    const int gn = n0 + wn * 64 + j * 16 + col16;
    const float bb_ = bias[gn];
#pragma unroll
    for (int i = 0; i < 8; ++i) {
      const int gm = m0 + wm * 128 + i * 16 + quad * 4;
#pragma unroll
      for (int r = 0; r < 4; ++r)
        dst[(size_t)(gm + r) * DD + gn] = (f16)(acc[i][j][r] + bb_);
    }
  }
}

// ---------------------------------------------------------------------------
// Transpose V [b][s][e] -> Vt [b][e][s], full batch (grid 32,16,8)
// ---------------------------------------------------------------------------
__global__ __launch_bounds__(256) void transpose_v(
    const f16* __restrict__ Vv, f16* __restrict__ Vt)
{
  __shared__ alignas(16) f16 tile[64][72];
  const int b  = blockIdx.z;
  const int s0 = blockIdx.x * 64;
  const int e0 = blockIdx.y * 64;
  const int t  = threadIdx.x;
  const int r  = t >> 3;
  const int c8 = (t & 7) * 8;

  const f16* src0 = Vv + ((size_t)(b * SS + s0 + r)) * DD + e0 + c8;
  const f16* src1 = Vv + ((size_t)(b * SS + s0 + r + 32)) * DD + e0 + c8;
  *(int4*)&tile[r][c8]      = *(const int4*)src0;
  *(int4*)&tile[r + 32][c8] = *(const int4*)src1;
  __syncthreads();

  f16x8 v0, v1;
#pragma unroll
  for (int u = 0; u < 8; ++u) {
    v0[u] = tile[c8 + u][r];
    v1[u] = tile[c8 + u][r + 32];
  }
  f16* dst0 = Vt + ((size_t)b * DD + e0 + r) * SS + s0 + c8;
  f16* dst1 = Vt + ((size_t)b * DD + e0 + r + 32) * SS + s0 + c8;
  *(f16x8*)dst0 = v0;
  *(f16x8*)dst1 = v1;
}

// ---------------------------------------------------------------------------
// Scores for chunk [b0, b0+c): grid (8, 8, c), 256x256 tiles.
// ---------------------------------------------------------------------------
__global__ __launch_bounds__(512, 2) void qk_gemm(
    const f16* __restrict__ Q, const f16* __restrict__ K, f16* __restrict__ Sc,
    int b0)
{
  __shared__ alignas(16) f16 As[4 * T32];
  __shared__ alignas(16) f16 Bs[4 * T32];

  const dim3 bid = xcd_swz();
  const int bb = bid.z;
  const int t = threadIdx.x, lane = t & 63, wave = t >> 6;
  const int wm = wave >> 2, wn = wave & 3, col16 = lane & 15, quad = lane >> 4;
  const int m0 = bid.y * 256, n0 = bid.x * 256;

  const size_t arow0 = (size_t)(b0 + bb) * SS + m0;
  const size_t brow0 = (size_t)(b0 + bb) * SS + n0;

  f32x4 acc[8][4];
#pragma unroll
  for (int i = 0; i < 8; ++i)
#pragma unroll
    for (int j = 0; j < 4; ++j) acc[i][j] = f32x4{0.f, 0.f, 0.f, 0.f};

  mma_pipeline<DD>(Q, K, DD, DD, arow0, brow0,
                   As, Bs, acc, wave, lane, wm, wn, col16, quad);

#pragma unroll
  for (int i = 0; i < 8; ++i)
#pragma unroll
    for (int j = 0; j < 4; ++j)
#pragma unroll
      for (int r = 0; r < 4; ++r) {
        const int gm = m0 + wm * 128 + i * 16 + quad * 4 + r;
        const int gn = n0 + wn * 64 + j * 16 + col16;
        Sc[((size_t)bb * SS + gm) * SS + gn] = (f16)acc[i][j][r];
      }
}

// ---------------------------------------------------------------------------
// Row softmax fp16 -> fp16, in place (row = 2048 f16; 256 thr x f16x8).
// ---------------------------------------------------------------------------
__global__ __launch_bounds__(256) void softmax_rows(f16* __restrict__ Sc)
{
  const size_t row = blockIdx.x;
  f16* p = Sc + row * SS;
  const int t = threadIdx.x;

  const f16x8 v = *(const f16x8*)(p + t * 8);
  float xs[8];
#pragma unroll
  for (int u = 0; u < 8; ++u) xs[u] = (float)v[u];

  float m = xs[0];
#pragma unroll
  for (int u = 1; u < 8; ++u) m = fmaxf(m, xs[u]);
#pragma unroll
  for (int off = 32; off > 0; off >>= 1) m = fmaxf(m, __shfl_xor(m, off));
  __shared__ float redm[4];
  __shared__ float reds[4];
  if ((t & 63) == 0) redm[t >> 6] = m;
  __syncthreads();
  m = fmaxf(fmaxf(redm[0], redm[1]), fmaxf(redm[2], redm[3]));

  float e[8];
  float s = 0.f;
#pragma unroll
  for (int u = 0; u < 8; ++u) {
    e[u] = expf(xs[u] - m);
    s += e[u];
  }
#pragma unroll
  for (int off = 32; off > 0; off >>= 1) s += __shfl_xor(s, off);
  if ((t & 63) == 0) reds[t >> 6] = s;
  __syncthreads();
  s = reds[0] + reds[1] + reds[2] + reds[3];
  const float inv = 1.0f / s;

  f16x8 o;
#pragma unroll
  for (int u = 0; u < 8; ++u) o[u] = (f16)(e[u] * inv);
  *(f16x8*)(p + t * 8) = o;
}

// ---------------------------------------------------------------------------
// Output: out[(b0+bb)][s][e] = sum_j P[bb][s][j] * Vt[b0+bb][e][j]
// grid (4, 8, c), 256x256 tiles, K = SS = 2048.
// ---------------------------------------------------------------------------
__global__ __launch_bounds__(512, 2) void pv_gemm(
    const f16* __restrict__ P, const f16* __restrict__ Vt, float* __restrict__ out,
    int b0)
{
  __shared__ alignas(16) f16 As[4 * T32];
  __shared__ alignas(16) f16 Bs[4 * T32];

  const dim3 bid = xcd_swz();
  const int bb = bid.z;
  const int t = threadIdx.x, lane = t & 63, wave = t >> 6;
  const int wm = wave >> 2, wn = wave & 3, col16 = lane & 15, quad = lane >> 4;
  const int m0 = bid.y * 256;  // s
  const int n0 = bid.x * 256;  // e

  const size_t arow0 = (size_t)bb * SS + m0;         // P rows (pitch SS)
  const size_t brow0 = (size_t)(b0 + bb) * DD + n0;  // Vt rows (pitch SS)

  f32x4 acc[8][4];
#pragma unroll
  for (int i = 0; i < 8; ++i)
#pragma unroll
    for (int j = 0; j < 4; ++j) acc[i][j] = f32x4{0.f, 0.f, 0.f, 0.f};

  mma_pipeline<SS>(P, Vt, SS, SS, arow0, brow0,
                   As, Bs, acc, wave, lane, wm, wn, col16, quad);

#pragma unroll
  for (int i = 0; i < 8; ++i)
#pragma unroll
    for (int j = 0; j < 4; ++j)
#pragma unroll
      for (int r = 0; r < 4; ++r) {
        const int gm = m0 + wm * 128 + i * 16 + quad * 4 + r;
        const int gn = n0 + wn * 64 + j * 16 + col16;
        out[((size_t)(b0 + bb) * SS + gm) * DD + gn] = acc[i][j][r];
      }
}

// ---------------------------------------------------------------------------
extern "C" void kernel_launch(void* const* d_in, const int* in_sizes, int n_in,
                              void* d_out, int out_size, void* d_ws, size_t ws_size,
                              hipStream_t stream)
{
  const float* t_out = (const float*)d_in[0];
  const float* c_out = (const float*)d_in[1];
  const float* Wq    = (const float*)d_in[2];
  const float* bq    = (const float*)d_in[3];
  const float* Wk    = (const float*)d_in[4];
  const float* bk    = (const float*)d_in[5];
  const float* Wv    = (const float*)d_in[6];
  const float* bv    = (const float*)d_in[7];
  float* out = (float*)d_out;

  // ---- sizes ----
  const size_t WELT  = (size_t)DD * DD;
  const size_t TD8   = (size_t)BB * SS * DD;             // 16.7M elems
  const size_t XH_B  = TD8 * sizeof(f16);                // 33.55 MB
  const size_t SC1_B = (size_t)SS * SS * sizeof(f16);    // 8.39 MB per batch

  // ---- pick Sc chunk c (pure function of ws_size -> graph-safe) ----
  const size_t FIXED = 3 * WELT * sizeof(f16) + 4 * XH_B;  // 140.5 MB
  int c = 2;
  for (int cand : {8, 4}) {
    size_t xsc = (size_t)cand * SC1_B;
    if (xsc < XH_B) xsc = XH_B;
    if (FIXED + xsc <= ws_size) { c = cand; break; }
  }
  size_t xsc_bytes = (size_t)c * SC1_B;
  if (xsc_bytes < XH_B) xsc_bytes = XH_B;

  // ---- layout: [W][Xh|Sc(alias)][Q][K][Vv][Vt] ----
  char* ws = (char*)d_ws;
  f16* Whq = (f16*)ws;
  f16* Whk = Whq + WELT;
  f16* Whv = Whk + WELT;
  char* XSc = (char*)(Whv + WELT);
  f16* Xh = (f16*)XSc;     // live during prep/proj
  f16* Sc = (f16*)XSc;     // live during attention chunks (aliases Xh)
  f16* Q  = (f16*)(XSc + xsc_bytes);
  f16* K  = Q  + TD8;
  f16* Vv = K  + TD8;
  f16* Vt = Vv + TD8;

  fused_prep<<<dim3(1024 + 16384), dim3(256), 0, stream>>>(
      Wq, Wk, Wv, t_out, c_out, Whq, Whk, Whv, Xh);
  proj_gemm<<<dim3(64, 4, 3), dim3(512), 0, stream>>>(
      Xh, Whq, Whk, Whv, bq, bk, bv, Q, K, Vv);
  transpose_v<<<dim3(32, 16, 8), dim3(256), 0, stream>>>(Vv, Vt);

  for (int b0 = 0; b0 < BB; b0 += c) {
    qk_gemm<<<dim3(8, 8, c), dim3(512), 0, stream>>>(Q, K, Sc, b0);
    softmax_rows<<<dim3(c * SS), dim3(256), 0, stream>>>(Sc);
    pv_gemm<<<dim3(4, 8, c), dim3(512), 0, stream>>>(Sc, Vt, out, b0);
  }
}